// Round 1
// 629.049 us; speedup vs baseline: 1.0406x; 1.0406x over previous
//
#include <hip/hip_runtime.h>
#include <math.h>

using u16 = unsigned short;
using u32 = unsigned int;

typedef __attribute__((ext_vector_type(4))) float f32x4;
typedef __attribute__((ext_vector_type(8))) short s16x8;

__device__ __forceinline__ u16 f2bf(float f) {
  union { float f; u32 u; } c; c.f = f;
  u32 u = c.u;
  u += 0x7fffu + ((u >> 16) & 1u);   // round-to-nearest-even
  return (u16)(u >> 16);
}
__device__ __forceinline__ float bf2f(u16 s) {
  union { u32 u; float f; } c; c.u = ((u32)s) << 16;
  return c.f;
}
__device__ __forceinline__ void async16(const void* g, void* l) {
  __builtin_amdgcn_global_load_lds(
      (const __attribute__((address_space(1))) void*)g,
      (__attribute__((address_space(3))) void*)l, 16, 0, 0);
}

// ---------------- LayerNorm: rows x 256 f32 -> bf16, one wave per row ----------------
__global__ __launch_bounds__(256) void ln_kernel(
    const float* __restrict__ x, const float* __restrict__ sc,
    const float* __restrict__ bi, u16* __restrict__ out) {
  const int w = threadIdx.x >> 6, l = threadIdx.x & 63;
  const int row = blockIdx.x * 4 + w;
  const float4 v = ((const float4*)(x + (size_t)row * 256))[l];
  float s  = v.x + v.y + v.z + v.w;
  float s2 = v.x * v.x + v.y * v.y + v.z * v.z + v.w * v.w;
#pragma unroll
  for (int m = 1; m < 64; m <<= 1) {
    s  += __shfl_xor(s,  m, 64);
    s2 += __shfl_xor(s2, m, 64);
  }
  const float mean = s * (1.0f / 256.0f);
  const float var  = s2 * (1.0f / 256.0f) - mean * mean;
  const float rs   = rsqrtf(var + 1e-5f);
  const float4 s4 = ((const float4*)sc)[l];
  const float4 b4 = ((const float4*)bi)[l];
  u16 o0 = f2bf((v.x - mean) * rs * s4.x + b4.x);
  u16 o1 = f2bf((v.y - mean) * rs * s4.y + b4.y);
  u16 o2 = f2bf((v.z - mean) * rs * s4.z + b4.z);
  u16 o3 = f2bf((v.w - mean) * rs * s4.w + b4.w);
  uint2 p; p.x = (u32)o0 | ((u32)o1 << 16); p.y = (u32)o2 | ((u32)o3 << 16);
  *(uint2*)(out + (size_t)row * 256 + l * 4) = p;
}

// ---------------- weight convert f32 [K][N] -> bf16 transposed [N][K] ----------------
__global__ __launch_bounds__(256) void convw_kernel(
    const float* s0, const float* s1, const float* s2, const float* s3,
    const float* s4, const float* s5,
    u16* d0, u16* d1, u16* d2, u16* d3, u16* d4, u16* d5) {
  const float* s; u16* d; int K, N, sh;
  switch (blockIdx.y) {
    case 0: s = s0; d = d0; K = 256; N = 256; sh = 8; break;  // Wq
    case 1: s = s1; d = d1; K = 256; N = 256; sh = 8; break;  // Wgate -> rows 256..511 of WQGT
    case 2: s = s2; d = d2; K = 256; N = 512; sh = 9; break;  // Wkv
    case 3: s = s3; d = d3; K = 256; N = 256; sh = 8; break;  // Wout
    case 4: s = s4; d = d4; K = 256; N = 512; sh = 9; break;  // W1
    default: s = s5; d = d5; K = 512; N = 256; sh = 8; break; // W2
  }
  const int idx = blockIdx.x * 256 + threadIdx.x;
  if (idx >= K * N) return;
  const int k = idx >> sh, n = idx & (N - 1);
  d[(size_t)n * K + k] = f2bf(s[idx]);
}

// ---------------- V transpose: KV v-part -> VT[n][h][c][j] (j contiguous) ----------------
__global__ __launch_bounds__(256) void vtrans_kernel(const u16* __restrict__ KV,
                                                     u16* __restrict__ VT) {
  const int n = blockIdx.x, h = blockIdx.y;
  const int t = threadIdx.x;
  const int j = t >> 2, cg = t & 3;
  union { uint4 v; u16 u[8]; } d;
  d.v = *(const uint4*)(KV + ((size_t)(j * 384 + n)) * 512 + 256 + h * 32 + cg * 8);
  u16* dst = VT + (((size_t)n * 8 + h) * 32 + cg * 8) * 64 + j;
#pragma unroll
  for (int c = 0; c < 8; c++) dst[c * 64] = d.u[c];
}

// ---------------- GEMM: C[M][N] = A[M][K] @ W, BT = W^T [N][K], bf16 MFMA ----------------
// 128x128 tile, BK=32, 4 waves (2x2), global_load_lds width 16, XOR chunk swizzle.
// NEW: 2-phase double-buffered LDS pipeline (stage tile t+1 before computing tile t, one
//      __syncthreads per iter so the implicit vmcnt(0) drain overlaps with MFMA work),
//      plus bijective XCD-aware tile swizzle (all grids are %8==0) so the gridDim.x
//      column-blocks sharing an A-panel land on the SAME XCD's L2.
// epi: 0 = store bf16; 1 = bf16(relu(acc+bias)); 2 = f32 res+acc*rmask; 3 = f32 out+=(acc+bias)*rmask
__global__ __launch_bounds__(256) void gemm_kernel(
    const u16* __restrict__ A, const u16* __restrict__ BT,
    const int K, const int N,
    u16* __restrict__ outb, float* __restrict__ outf,
    const float* __restrict__ bias, const float* __restrict__ res,
    const int* __restrict__ rmask, const int epi) {
  __shared__ u16 Als[2][128 * 32];
  __shared__ u16 Bls[2][128 * 32];
  const int t = threadIdx.x, w = t >> 6, l = t & 63;
  const int lm = l & 15, lk = l >> 4;

  // XCD-aware bijective swizzle: hw id % 8 ~= XCD; give each XCD a contiguous
  // chunk of the original tile space so same-A-panel blocks share one L2.
  const int nwg = gridDim.x * gridDim.y;
  const int hw = blockIdx.y * gridDim.x + blockIdx.x;
  int wid = hw;
  if (!(nwg & 7)) wid = (hw & 7) * (nwg >> 3) + (hw >> 3);
  const int gxsh = __builtin_ctz(gridDim.x);     // gridDim.x is 2 or 4 (pow2)
  const int nb = (wid & (gridDim.x - 1)) * 128;
  const int mb = (wid >> gxsh) * 128;

  // staging: wave w stages rows w*32..w*32+31 of both tiles; lane -> (row=l>>2, chunk)
  const int cg = (l & 3) ^ ((l >> 3) & 3);           // swizzled global 16B-chunk
  const int rA = w * 32 + (l >> 2);
  const u16* gA = A  + (size_t)(mb + rA) * K + cg * 8;
  const u16* gB = BT + (size_t)(nb + rA) * K + cg * 8;
  const size_t rk16 = (size_t)16 * K;
  const int lofs = (w * 32) * 32;                    // element offset of wave's stage rows

  const int pc = (lk ^ ((l >> 1) & 3)) * 8;          // swizzled read chunk (elements)
  const int m0 = (w >> 1) * 64, n0 = (w & 1) * 64;

  f32x4 acc[4][4] = {};

  // prologue: stage K-tile 0 into buffer 0
  async16(gA,        &Als[0][lofs]);
  async16(gA + rk16, &Als[0][lofs + 16 * 32]);
  async16(gB,        &Bls[0][lofs]);
  async16(gB + rk16, &Bls[0][lofs + 16 * 32]);
  __syncthreads();

  const int nk = K >> 5;
  int buf = 0;
  for (int tt = 0; tt < nk; ++tt) {
    // issue next tile's loads BEFORE computing current tile (overlap)
    if (tt + 1 < nk) {
      const int kk = (tt + 1) << 5;
      const int nbuf = buf ^ 1;
      async16(gA + kk,        &Als[nbuf][lofs]);
      async16(gA + rk16 + kk, &Als[nbuf][lofs + 16 * 32]);
      async16(gB + kk,        &Bls[nbuf][lofs]);
      async16(gB + rk16 + kk, &Bls[nbuf][lofs + 16 * 32]);
    }
    s16x8 a[4], b[4];
#pragma unroll
    for (int i = 0; i < 4; i++) a[i] = *(const s16x8*)&Als[buf][(m0 + i * 16 + lm) * 32 + pc];
#pragma unroll
    for (int j = 0; j < 4; j++) b[j] = *(const s16x8*)&Bls[buf][(n0 + j * 16 + lm) * 32 + pc];
#pragma unroll
    for (int i = 0; i < 4; i++)
#pragma unroll
      for (int j = 0; j < 4; j++)
        acc[i][j] = __builtin_amdgcn_mfma_f32_16x16x32_bf16(a[i], b[j], acc[i][j], 0, 0, 0);
    // drains the 4 in-flight prefetch loads (vmcnt(0)) AFTER the MFMA work hid them,
    // and guards the buffer swap.
    __syncthreads();
    buf ^= 1;
  }

  const int r0 = mb + m0 + lk * 4;   // + i*16 + r
  const int c0 = nb + n0 + lm;       // + j*16
  if (epi == 0) {
#pragma unroll
    for (int i = 0; i < 4; i++)
#pragma unroll
      for (int j = 0; j < 4; j++)
#pragma unroll
        for (int r = 0; r < 4; r++)
          outb[(size_t)(r0 + i * 16 + r) * N + (c0 + j * 16)] = f2bf(acc[i][j][r]);
  } else if (epi == 1) {
#pragma unroll
    for (int i = 0; i < 4; i++)
#pragma unroll
      for (int j = 0; j < 4; j++)
#pragma unroll
        for (int r = 0; r < 4; r++) {
          const int col = c0 + j * 16;
          const float v = fmaxf(acc[i][j][r] + bias[col], 0.0f);
          outb[(size_t)(r0 + i * 16 + r) * N + col] = f2bf(v);
        }
  } else if (epi == 2) {
#pragma unroll
    for (int i = 0; i < 4; i++)
#pragma unroll
      for (int r = 0; r < 4; r++) {
        const int row = r0 + i * 16 + r;
        const float rm = (float)rmask[row];
#pragma unroll
        for (int j = 0; j < 4; j++) {
          const size_t idx = (size_t)row * N + (c0 + j * 16);
          outf[idx] = res[idx] + acc[i][j][r] * rm;
        }
      }
  } else {
#pragma unroll
    for (int i = 0; i < 4; i++)
#pragma unroll
      for (int r = 0; r < 4; r++) {
        const int row = r0 + i * 16 + r;
        const float rm = (float)rmask[row];
#pragma unroll
        for (int j = 0; j < 4; j++) {
          const int col = c0 + j * 16;
          const size_t idx = (size_t)row * N + col;
          outf[idx] = outf[idx] + (acc[i][j][r] + bias[col]) * rm;
        }
      }
  }
}

// ---------------- attention: softmax over HEADS (axis=-1 of bijnh!), mask cancels ----------------
// block = (n, ig): 16 i-rows x 64 j x 8 h. Phase1: per-wave jt, all 8 h -> per-lane h-softmax.
// Phase2: P via LDS -> PV with V^T, fused sigmoid(gate).
__global__ __launch_bounds__(256) void attn_kernel(
    const u16* __restrict__ QG, const u16* __restrict__ KV,
    const u16* __restrict__ VT, u16* __restrict__ O) {
  __shared__ u16 P[8][16][72];   // [h][i][j], pad 64->72 to kill read bank conflicts
  const int n = blockIdx.x, ig = blockIdx.y;
  const int t = threadIdx.x, w = t >> 6, l = t & 63;
  const int lm = l & 15, lk = l >> 4;

  const u16* qb = QG + ((size_t)(ig * 16 + lm) * 384 + n) * 512 + lk * 8;
  const u16* kb = KV + ((size_t)(w * 16 + lm) * 384 + n) * 512 + lk * 8;
  const f32x4 zz = {0.f, 0.f, 0.f, 0.f};
  f32x4 acc[8];
#pragma unroll
  for (int h = 0; h < 8; h++) {
    s16x8 af = *(const s16x8*)(qb + h * 32);
    s16x8 bf = *(const s16x8*)(kb + h * 32);
    acc[h] = __builtin_amdgcn_mfma_f32_16x16x32_bf16(af, bf, zz, 0, 0, 0);
  }
  // per-lane softmax over h for each of 4 rows (C-layout: row=lk*4+r, col j=w*16+lm)
#pragma unroll
  for (int r = 0; r < 4; r++) {
    float mx = acc[0][r];
#pragma unroll
    for (int h = 1; h < 8; h++) mx = fmaxf(mx, acc[h][r]);
    float e[8], s = 0.f;
#pragma unroll
    for (int h = 0; h < 8; h++) { e[h] = __expf(acc[h][r] - mx); s += e[h]; }
    const float inv = 1.0f / s;
#pragma unroll
    for (int h = 0; h < 8; h++) P[h][lk * 4 + r][w * 16 + lm] = f2bf(e[h] * inv);
  }
  __syncthreads();

  const u16* vb = VT + ((size_t)n * 8) * 2048;   // [h][c 32][j 64]
#pragma unroll
  for (int hh = 0; hh < 2; hh++) {
    const int h = w * 2 + hh;
#pragma unroll
    for (int nt = 0; nt < 2; nt++) {
      f32x4 o = zz;
#pragma unroll
      for (int ks = 0; ks < 2; ks++) {
        s16x8 af = *(const s16x8*)&P[h][lm][ks * 32 + lk * 8];
        s16x8 bf = *(const s16x8*)(vb + (size_t)h * 2048 + (nt * 16 + lm) * 64 + ks * 32 + lk * 8);
        o = __builtin_amdgcn_mfma_f32_16x16x32_bf16(af, bf, o, 0, 0, 0);
      }
#pragma unroll
      for (int r = 0; r < 4; r++) {
        const int i = ig * 16 + lk * 4 + r;
        const int col = h * 32 + nt * 16 + lm;
        const size_t orow = (size_t)i * 384 + n;
        const float g = bf2f(QG[orow * 512 + 256 + col]);
        const float val = o[r] / (1.0f + __expf(-g));   // out * sigmoid(gate)
        O[orow * 256 + col] = f2bf(val);
      }
    }
  }
}

extern "C" void kernel_launch(void* const* d_in, const int* in_sizes, int n_in,
                              void* d_out, int out_size, void* d_ws, size_t ws_size,
                              hipStream_t stream) {
  (void)in_sizes; (void)n_in; (void)out_size; (void)ws_size;
  const float* embed  = (const float*)d_in[0];
  const float* memory = (const float*)d_in[1];
  const int*   rmask  = (const int*)d_in[2];
  // d_in[3] memory_mask: provably no effect (softmax over h cancels the bias)
  const float* lnqs = (const float*)d_in[4];
  const float* lnqb = (const float*)d_in[5];
  const float* lnks = (const float*)d_in[6];
  const float* lnkb = (const float*)d_in[7];
  const float* Wq   = (const float*)d_in[8];
  const float* Wkv  = (const float*)d_in[9];
  const float* Wg   = (const float*)d_in[10];
  const float* Wo   = (const float*)d_in[11];
  const float* lnfs = (const float*)d_in[12];
  const float* lnfb = (const float*)d_in[13];
  const float* W1   = (const float*)d_in[14];
  const float* b1   = (const float*)d_in[15];
  const float* W2   = (const float*)d_in[16];
  const float* b2   = (const float*)d_in[17];
  float* out = (float*)d_out;
  char* ws = (char*)d_ws;

  // workspace layout (peak 240.3 MB, with aliasing)
  u16* qe   = (u16*)(ws + 0);              // 98304x256 bf16
  u16* km   = (u16*)(ws + 50331648);       // 24576x256 bf16
  u16* VT   = km;                          // aliases km (dead after KV GEMM): 384*8*32*64
  u16* QG   = (u16*)(ws + 62914560);       // 98304x512 bf16 (q | gate)
  u16* h1   = QG;                          // aliases QG (dead after attention)
  u16* KV   = (u16*)(ws + 163577856);      // 24576x512 bf16 (k | v)
  u16* O    = (u16*)(ws + 188743680);      // 98304x256 bf16 gated attn out
  u16* WQGT = (u16*)(ws + 239075328);      // [512][256]
  u16* WKVT = WQGT + 131072;               // [512][256]
  u16* WOUTT= WKVT + 131072;               // [256][256]
  u16* W1T  = WOUTT + 65536;               // [512][256]
  u16* W2T  = W1T + 131072;                // [256][512]
  u16* lnx  = qe;                          // aliases qe (dead after QG GEMM)

  convw_kernel<<<dim3(512, 6), 256, 0, stream>>>(Wq, Wg, Wkv, Wo, W1, W2,
      WQGT, WQGT + 65536, WKVT, WOUTT, W1T, W2T);
  ln_kernel<<<24576, 256, 0, stream>>>(embed, lnqs, lnqb, qe);
  ln_kernel<<<6144, 256, 0, stream>>>(memory, lnks, lnkb, km);
  gemm_kernel<<<dim3(4, 768), 256, 0, stream>>>(qe, WQGT, 256, 512, QG, nullptr, nullptr, nullptr, nullptr, 0);
  gemm_kernel<<<dim3(4, 192), 256, 0, stream>>>(km, WKVT, 256, 512, KV, nullptr, nullptr, nullptr, nullptr, 0);
  vtrans_kernel<<<dim3(384, 8), 256, 0, stream>>>(KV, VT);
  attn_kernel<<<dim3(384, 16), 256, 0, stream>>>(QG, KV, VT, O);
  gemm_kernel<<<dim3(2, 768), 256, 0, stream>>>(O, WOUTT, 256, 256, nullptr, out, nullptr, embed, rmask, 2);
  ln_kernel<<<24576, 256, 0, stream>>>(out, lnfs, lnfb, lnx);
  gemm_kernel<<<dim3(4, 768), 256, 0, stream>>>(lnx, W1T, 256, 512, h1, nullptr, b1, nullptr, nullptr, 1);
  gemm_kernel<<<dim3(2, 768), 256, 0, stream>>>(h1, W2T, 512, 256, nullptr, out, b2, nullptr, rmask, 3);
}